// Round 15
// baseline (227.626 us; speedup 1.0000x reference)
//
#include <hip/hip_runtime.h>
#include <hip/hip_fp16.h>

typedef _Float16 f16x8 __attribute__((ext_vector_type(8)));
typedef _Float16 f16x4 __attribute__((ext_vector_type(4)));
typedef float    f32x4 __attribute__((ext_vector_type(4)));

#define MFMA16(a,b,c) __builtin_amdgcn_mfma_f32_16x16x32_f16(a,b,c,0,0,0)

__device__ __forceinline__ void gload_lds16(const void* g, void* l) {
  __builtin_amdgcn_global_load_lds(
      (const __attribute__((address_space(1))) void*)g,
      (__attribute__((address_space(3))) void*)l, 16, 0, 0);
}

// ---------------- fp32 -> fp16 conversion (X only) ----------------
__global__ void cvt_f32_f16(const float* __restrict__ src,
                            _Float16* __restrict__ dst, int n8) {
  int i = blockIdx.x * blockDim.x + threadIdx.x;
  int stride = gridDim.x * blockDim.x;
  for (; i < n8; i += stride) {
    const float4* s = (const float4*)src + 2 * (size_t)i;
    float4 a = s[0], b = s[1];
    f16x8 o;
    o[0]=(_Float16)a.x; o[1]=(_Float16)a.y; o[2]=(_Float16)a.z; o[3]=(_Float16)a.w;
    o[4]=(_Float16)b.x; o[5]=(_Float16)b.y; o[6]=(_Float16)b.z; o[7]=(_Float16)b.w;
    ((f16x8*)dst)[i] = o;
  }
}

// ---------------- fused QKV GEMM (R5 structure, proven ~120us) ----------------
// C[512,12288] = X16 @ [Wq;Wk;Wv]^T. Tile 128m x 64n, BK=64, 768 blocks (3/CU).
// Writes Q16 full; K16 rows [P,P+512); V16t cols [P,P+512). No cache cvt needed.
__global__ __launch_bounds__(256) void qkv_gemm(
    const _Float16* __restrict__ X,
    const float* __restrict__ Wq,
    const float* __restrict__ Wk,
    const float* __restrict__ Wv,
    _Float16* __restrict__ Q16,
    _Float16* __restrict__ Kc,
    _Float16* __restrict__ Vt16,
    const int* __restrict__ Pp)
{
  __shared__ __align__(16) _Float16 As[128 * 64];   // 16KB, 128B rows, XOR-swizzled
  __shared__ __align__(16) _Float16 Bs[64 * 64];    // 8KB,  128B rows, XOR-swizzled
  const int bid = blockIdx.x;                 // 768 = 8 xcd * 96
  const int xcd = bid & 7, s = bid >> 3;
  const int nt = xcd * 24 + (s >> 2);
  const int mt = s & 3;
  const int m0 = mt * 128, n0 = nt * 64;
  const int tid = threadIdx.x, wave = tid >> 6, lane = tid & 63;
  const int g = lane >> 4, c = lane & 15;
  const int wr = wave >> 1, wc = wave & 1;    // wave = 64m x 32n
  const float* Wp = (n0 < 4096) ? Wq : ((n0 < 8192) ? Wk : Wv);
  const int n0l = n0 & 4095;
  const int ar  = lane >> 3;
  const int acs = (lane & 7) * 16;
  const int brow = tid >> 2;
  const int bc32 = (tid & 3) * 16;
  const float* wsrc = Wp + (size_t)(n0l + brow) * 4096 + bc32;
  const int bsw = (brow & 7) << 4;
  float4 breg[4];
#pragma unroll
  for (int i = 0; i < 4; i++) breg[i] = *(const float4*)(wsrc + i * 4);

  f32x4 acc[4][2] = {};
  for (int k0 = 0; k0 < 4096; k0 += 64) {
    __syncthreads();
#pragma unroll
    for (int p = 0; p < 4; p++) {
      int chunk = wave * 4 + p;
      int row = chunk * 8 + ar;
      gload_lds16((const char*)(X + (size_t)(m0 + row) * 4096 + k0) + (acs ^ ((row & 7) << 4)),
                  (char*)As + chunk * 1024);
    }
    {
      const float* bv = (const float*)breg;
      f16x8 h0, h1;
#pragma unroll
      for (int i = 0; i < 8; i++) { h0[i] = (_Float16)bv[i]; h1[i] = (_Float16)bv[8 + i]; }
      char* rb = (char*)Bs + brow * 128;
      *(f16x8*)(rb + (((tid & 3) * 32)      ^ bsw)) = h0;
      *(f16x8*)(rb + (((tid & 3) * 32 + 16) ^ bsw)) = h1;
      if (k0 + 64 < 4096) {
        const float* ns = wsrc + k0 + 64;
#pragma unroll
        for (int i = 0; i < 4; i++) breg[i] = *(const float4*)(ns + i * 4);
      }
    }
    __syncthreads();
    f16x8 af[2][4], bf[2][2];
#pragma unroll
    for (int mi = 0; mi < 4; mi++) {
      int row = wr * 64 + mi * 16 + c;
      int sw = (row & 7) << 4;
#pragma unroll
      for (int kc = 0; kc < 2; kc++)
        af[kc][mi] = *(const f16x8*)((const char*)As + row * 128 + ((kc * 64 + g * 16) ^ sw));
    }
#pragma unroll
    for (int ni = 0; ni < 2; ni++) {
      int row = wc * 32 + ni * 16 + c;
      int sw = (row & 7) << 4;
#pragma unroll
      for (int kc = 0; kc < 2; kc++)
        bf[kc][ni] = *(const f16x8*)((const char*)Bs + row * 128 + ((kc * 64 + g * 16) ^ sw));
    }
#pragma unroll
    for (int kc = 0; kc < 2; kc++)
#pragma unroll
      for (int mi = 0; mi < 4; mi++)
#pragma unroll
        for (int ni = 0; ni < 2; ni++)
          acc[mi][ni] = MFMA16(af[kc][mi], bf[kc][ni], acc[mi][ni]);
  }
  const int p = Pp[0];
  const int wsel = n0 >> 12;
  const int h = (n0 & 4095) >> 7;
  const int dbase = n0 & 127;                 // 0 or 64
#pragma unroll
  for (int mi = 0; mi < 4; mi++) {
#pragma unroll
    for (int ni = 0; ni < 2; ni++) {
#pragma unroll
      for (int j = 0; j < 4; j++) {
        int m = m0 + wr * 64 + mi * 16 + 4 * g + j;
        int d = dbase + wc * 32 + ni * 16 + c;
        _Float16 hv = (_Float16)acc[mi][ni][j];
        if (wsel == 0)      Q16[(size_t)(h * 512 + m) * 128 + d] = hv;
        else if (wsel == 1) Kc[(size_t)(h * 4096 + p + m) * 128 + d] = hv;
        else                Vt16[((size_t)h * 128 + d) * 4096 + p + m] = hv;
      }
    }
  }
}

// ---------------- flash attention: stages K/V DIRECTLY from f32 caches ----------------
// grid 512 = 8 XCD x (4 groups x 4 mt); 8 waves x 16 q-rows; BL=64.
// Per tile: reg-load (f32 cache, cvt) or (f16 gemm output for l in [P,P+512)),
// swizzled ds_write; T14: next tile's loads issued before compute. Opart f16.
__global__ __launch_bounds__(512, 4) void attn_part(
    const _Float16* __restrict__ Q16,
    const _Float16* __restrict__ K16,    // [32][4096][128] f16, valid rows [P,P+512)
    const _Float16* __restrict__ Vt,     // [32][128][4096] f16, valid cols [P,P+512)
    const float* __restrict__ cK,        // [32][4096][128] f32
    const float* __restrict__ cV,        // [32][4096][128] f32
    _Float16* __restrict__ Opart,        // [4][32][512][128] f16
    float* __restrict__ Mpart,           // [4][32][512]
    float* __restrict__ Lpart,           // [4][32][512]
    const int* __restrict__ Pp)
{
  __shared__ __align__(16) _Float16 Ks[64 * 128];     // 16KB: [l][d], swizzled
  __shared__ __align__(16) _Float16 Vs[128 * 64];     // 16KB: [d][l], swizzled
  __shared__ __align__(16) _Float16 Pl[8][16][68];    // 17KB
  const int bid = blockIdx.x;
  const int xcd = bid & 7, s = bid >> 3;
  const int group = xcd * 16 + (s >> 2);              // ls*32+h
  const int mt = s & 3;
  const int ls = group >> 5, h = group & 31;
  const int m0 = mt * 128;
  const int tid = threadIdx.x, wave = tid >> 6, lane = tid & 63;
  const int g = lane >> 4, c = lane & 15;
  const int mw = m0 + wave * 16;
  const int p = Pp[0];
  const _Float16* K16h = K16 + (size_t)h * 4096 * 128;
  const _Float16* Vth  = Vt  + (size_t)h * 128 * 4096;
  const float* cKh = cK + (size_t)h * 4096 * 128;
  const float* cVh = cV + (size_t)h * 4096 * 128;
  f16x8 qf[4];
#pragma unroll
  for (int kc = 0; kc < 4; kc++)
    qf[kc] = *(const f16x8*)&Q16[(size_t)(h * 512 + mw + c) * 128 + kc * 32 + g * 8];
  f32x4 o[8] = {};
  float mrow[4] = {-3e38f, -3e38f, -3e38f, -3e38f};
  float lrow[4] = {0.f, 0.f, 0.f, 0.f};

  // staging lane constants
  const int kr = tid >> 3, kq = tid & 7;              // K: row 0..63, 16-f32 col chunk
  const int ksw = (kr & 7) << 4;
  const int dp = (tid & 63) * 2, lg = tid >> 6;       // V: d-pair, l-group of 8
  float4 ka4[4];                                       // K raw (f32:16f32 / f16:2xf16x8)
  float4 va4[4];                                       // V raw (f32:8xf32 pairs / f16:2 rows)
  bool cur16 = false;

  auto loadTile = [&](int l0) {
    bool is16 = ((unsigned)(l0 - p) < 512u);
    cur16 = is16;
    if (!is16) {
      const float* ks = cKh + (size_t)(l0 + kr) * 128 + kq * 16;
#pragma unroll
      for (int i = 0; i < 4; i++) ka4[i] = ((const float4*)ks)[i];
      const float* vs0 = cVh + (size_t)(l0 + lg * 8) * 128 + dp;
#pragma unroll
      for (int i = 0; i < 4; i++) {
        float2 a = *(const float2*)(vs0 + (size_t)(2 * i) * 128);
        float2 b = *(const float2*)(vs0 + (size_t)(2 * i + 1) * 128);
        va4[i] = make_float4(a.x, a.y, b.x, b.y);
      }
    } else {
      const _Float16* ks = K16h + (size_t)(l0 + kr) * 128 + kq * 16;
      ka4[0] = *(const float4*)(ks);
      ka4[1] = *(const float4*)(ks + 8);
      const _Float16* vs0 = Vth + (size_t)dp * 4096 + l0 + lg * 8;
      va4[0] = *(const float4*)(vs0);
      va4[1] = *(const float4*)(vs0 + 4096);
    }
  };
  auto writeTile = [&]() {
    f16x8 h0, h1;
    if (!cur16) {
      h0[0]=(_Float16)ka4[0].x; h0[1]=(_Float16)ka4[0].y; h0[2]=(_Float16)ka4[0].z; h0[3]=(_Float16)ka4[0].w;
      h0[4]=(_Float16)ka4[1].x; h0[5]=(_Float16)ka4[1].y; h0[6]=(_Float16)ka4[1].z; h0[7]=(_Float16)ka4[1].w;
      h1[0]=(_Float16)ka4[2].x; h1[1]=(_Float16)ka4[2].y; h1[2]=(_Float16)ka4[2].z; h1[3]=(_Float16)ka4[2].w;
      h1[4]=(_Float16)ka4[3].x; h1[5]=(_Float16)ka4[3].y; h1[6]=(_Float16)ka4[3].z; h1[7]=(_Float16)ka4[3].w;
    } else {
      h0 = *(f16x8*)&ka4[0];
      h1 = *(f16x8*)&ka4[1];
    }
    char* rb = (char*)Ks + kr * 256;
    *(f16x8*)(rb + ((kq * 32)      ^ ksw)) = h0;
    *(f16x8*)(rb + ((kq * 32 + 16) ^ ksw)) = h1;
    f16x8 v0, v1;
    if (!cur16) {
      v0[0]=(_Float16)va4[0].x; v0[1]=(_Float16)va4[0].z; v0[2]=(_Float16)va4[1].x; v0[3]=(_Float16)va4[1].z;
      v0[4]=(_Float16)va4[2].x; v0[5]=(_Float16)va4[2].z; v0[6]=(_Float16)va4[3].x; v0[7]=(_Float16)va4[3].z;
      v1[0]=(_Float16)va4[0].y; v1[1]=(_Float16)va4[0].w; v1[2]=(_Float16)va4[1].y; v1[3]=(_Float16)va4[1].w;
      v1[4]=(_Float16)va4[2].y; v1[5]=(_Float16)va4[2].w; v1[6]=(_Float16)va4[3].y; v1[7]=(_Float16)va4[3].w;
    } else {
      v0 = *(f16x8*)&va4[0];
      v1 = *(f16x8*)&va4[1];
    }
    *(f16x8*)((char*)Vs + (size_t)dp * 128       + ((lg * 16) ^ ((dp & 7) << 4)))       = v0;
    *(f16x8*)((char*)Vs + (size_t)(dp + 1) * 128 + ((lg * 16) ^ (((dp + 1) & 7) << 4))) = v1;
  };

  const int l_begin = ls * 1024;
  loadTile(l_begin);
  for (int l0 = l_begin; l0 < l_begin + 1024; l0 += 64) {
    __syncthreads();                 // prev compute done reading Ks/Vs
    writeTile();                     // cvt + swizzled ds_write (regs from prev loadTile)
    if (l0 + 64 < l_begin + 1024) loadTile(l0 + 64);   // T14: issue early, lands under compute
    __syncthreads();                 // staged tile visible
    // ---- QK^T ----
    f32x4 sc[4] = {};
#pragma unroll
    for (int ni = 0; ni < 4; ni++) {
      int krr = ni * 16 + c;
      f16x8 kf[4];
#pragma unroll
      for (int kc = 0; kc < 4; kc++)
        kf[kc] = *(const f16x8*)((const char*)Ks + krr * 256 + ((kc * 64 + g * 16) ^ ((krr & 7) << 4)));
#pragma unroll
      for (int kc = 0; kc < 4; kc++)
        sc[ni] = MFMA16(qf[kc], kf[kc], sc[ni]);
    }
    // ---- online softmax ----
    float scale[4];
#pragma unroll
    for (int j = 0; j < 4; j++) {
      float tm = sc[0][j];
#pragma unroll
      for (int ni = 1; ni < 4; ni++) tm = fmaxf(tm, sc[ni][j]);
      tm = fmaxf(tm, __shfl_xor(tm, 1, 64));
      tm = fmaxf(tm, __shfl_xor(tm, 2, 64));
      tm = fmaxf(tm, __shfl_xor(tm, 4, 64));
      tm = fmaxf(tm, __shfl_xor(tm, 8, 64));
      float mn = fmaxf(mrow[j], tm);
      scale[j] = __expf(mrow[j] - mn);
      mrow[j] = mn;
    }
    float rs[4] = {0.f, 0.f, 0.f, 0.f};
#pragma unroll
    for (int ni = 0; ni < 4; ni++) {
#pragma unroll
      for (int j = 0; j < 4; j++) {
        float pv = __expf(sc[ni][j] - mrow[j]);
        sc[ni][j] = pv;
        rs[j] += pv;
      }
    }
#pragma unroll
    for (int j = 0; j < 4; j++) {
      rs[j] += __shfl_xor(rs[j], 1, 64);
      rs[j] += __shfl_xor(rs[j], 2, 64);
      rs[j] += __shfl_xor(rs[j], 4, 64);
      rs[j] += __shfl_xor(rs[j], 8, 64);
      lrow[j] = lrow[j] * scale[j] + rs[j];
    }
#pragma unroll
    for (int dn = 0; dn < 8; dn++)
#pragma unroll
      for (int j = 0; j < 4; j++) o[dn][j] *= scale[j];
    // ---- P -> wave-private LDS ----
#pragma unroll
    for (int ni = 0; ni < 4; ni++)
#pragma unroll
      for (int j = 0; j < 4; j++)
        Pl[wave][4 * g + j][ni * 16 + c] = (_Float16)sc[ni][j];
    f16x8 pa[2];
#pragma unroll
    for (int kc = 0; kc < 2; kc++)
      pa[kc] = *(const f16x8*)&Pl[wave][c][kc * 32 + g * 8];
    // ---- PV ----
#pragma unroll
    for (int dn = 0; dn < 8; dn++) {
      int vr = dn * 16 + c;
#pragma unroll
      for (int kc = 0; kc < 2; kc++) {
        f16x8 vb = *(const f16x8*)((const char*)Vs + vr * 128 + ((kc * 64 + g * 16) ^ ((vr & 7) << 4)));
        o[dn] = MFMA16(pa[kc], vb, o[dn]);
      }
    }
  }
  // ---- epilogue (f16 partials) ----
  const size_t pbase = ((size_t)(ls * 32 + h) * 512);
#pragma unroll
  for (int dn = 0; dn < 8; dn++) {
#pragma unroll
    for (int j = 0; j < 4; j++) {
      int m = mw + 4 * g + j;
      Opart[(pbase + m) * 128 + dn * 16 + c] = (_Float16)o[dn][j];
    }
  }
  if (c == 0) {
#pragma unroll
    for (int j = 0; j < 4; j++) {
      int m = mw + 4 * g + j;
      Mpart[pbase + m] = mrow[j];
      Lpart[pbase + m] = lrow[j];
    }
  }
}

// ---------------- combine 4 split-L partials (f16 Opart) ----------------
__global__ __launch_bounds__(256) void attn_combine(
    const _Float16* __restrict__ Opart,
    const float* __restrict__ Mpart,
    const float* __restrict__ Lpart,
    float* __restrict__ out)
{
  int idx = blockIdx.x * 256 + threadIdx.x;
  int row = idx >> 5;
  int d4  = idx & 31;
  int h = row >> 9, m = row & 511;
  float Ms[4];
  float mx = -3e38f;
#pragma unroll
  for (int s = 0; s < 4; s++) {
    Ms[s] = Mpart[(size_t)(s * 32 + h) * 512 + m];
    mx = fmaxf(mx, Ms[s]);
  }
  float lsum = 0.f;
  float4 acc = make_float4(0.f, 0.f, 0.f, 0.f);
#pragma unroll
  for (int s = 0; s < 4; s++) {
    float w = __expf(Ms[s] - mx);
    lsum += w * Lpart[(size_t)(s * 32 + h) * 512 + m];
    f16x4 ov = *(const f16x4*)(Opart + ((size_t)(s * 32 + h) * 512 + m) * 128 + d4 * 4);
    acc.x += w * (float)ov[0]; acc.y += w * (float)ov[1];
    acc.z += w * (float)ov[2]; acc.w += w * (float)ov[3];
  }
  float inv = 1.f / lsum;
  float4 r = make_float4(acc.x * inv, acc.y * inv, acc.z * inv, acc.w * inv);
  *(float4*)&out[(size_t)m * 4096 + h * 128 + d4 * 4] = r;
}

extern "C" void kernel_launch(void* const* d_in, const int* in_sizes, int n_in,
                              void* d_out, int out_size, void* d_ws, size_t ws_size,
                              hipStream_t stream) {
  const float* X  = (const float*)d_in[0];
  const float* Wq = (const float*)d_in[1];
  const float* Wk = (const float*)d_in[2];
  const float* Wv = (const float*)d_in[3];
  const float* cK = (const float*)d_in[4];
  const float* cV = (const float*)d_in[5];
  const int*   Pp = (const int*)d_in[6];
  float* out = (float*)d_out;

  char* ws = (char*)d_ws;
  _Float16* X16  = (_Float16*)(ws);                           // 0..4 MB
  _Float16* Opart = (_Float16*)(ws + ((size_t)4  << 20));     // 4..20 MB [4][32][512][128] f16
  float* Mpart = (float*)(ws + ((size_t)36 << 20));
  float* Lpart = (float*)(ws + ((size_t)37 << 20));
  _Float16* Q16  = (_Float16*)(ws + ((size_t)100 << 20));     // 100..104
  _Float16* K16  = (_Float16*)(ws + ((size_t)104 << 20));     // 104..136 [32][4096][128]
  _Float16* V16t = (_Float16*)(ws + ((size_t)136 << 20));     // 136..168 [32][128][4096]

  cvt_f32_f16<<<dim3(1024), dim3(256), 0, stream>>>(X, X16, 512 * 4096 / 8);
  qkv_gemm<<<dim3(768), dim3(256), 0, stream>>>(X16, Wq, Wk, Wv, Q16, K16, V16t, Pp);
  attn_part<<<dim3(512), dim3(512), 0, stream>>>(Q16, K16, V16t, cK, cV,
                                                 Opart, Mpart, Lpart, Pp);
  attn_combine<<<dim3(2048), dim3(256), 0, stream>>>(Opart, Mpart, Lpart, out);
}

// Round 16
// 217.828 us; speedup vs baseline: 1.0450x; 1.0450x over previous
//
#include <hip/hip_runtime.h>
#include <hip/hip_fp16.h>

typedef _Float16 f16x8 __attribute__((ext_vector_type(8)));
typedef _Float16 f16x4 __attribute__((ext_vector_type(4)));
typedef float    f32x4 __attribute__((ext_vector_type(4)));

#define MFMA16(a,b,c) __builtin_amdgcn_mfma_f32_16x16x32_f16(a,b,c,0,0,0)

__device__ __forceinline__ void gload_lds16(const void* g, void* l) {
  __builtin_amdgcn_global_load_lds(
      (const __attribute__((address_space(1))) void*)g,
      (__attribute__((address_space(3))) void*)l, 16, 0, 0);
}

// ---------------- fp32 -> fp16 conversion (X only) ----------------
__global__ void cvt_f32_f16(const float* __restrict__ src,
                            _Float16* __restrict__ dst, int n8) {
  int i = blockIdx.x * blockDim.x + threadIdx.x;
  int stride = gridDim.x * blockDim.x;
  for (; i < n8; i += stride) {
    const float4* s = (const float4*)src + 2 * (size_t)i;
    float4 a = s[0], b = s[1];
    f16x8 o;
    o[0]=(_Float16)a.x; o[1]=(_Float16)a.y; o[2]=(_Float16)a.z; o[3]=(_Float16)a.w;
    o[4]=(_Float16)b.x; o[5]=(_Float16)b.y; o[6]=(_Float16)b.z; o[7]=(_Float16)b.w;
    ((f16x8*)dst)[i] = o;
  }
}

// ---------------- fused: QKV GEMM (768 blocks, dbuf 2-phase) + K/V cache cvt ----------------
// GEMM: 128m x 64n, BK=64, dbuf (one barrier/iter). cvt blocks fill latency bubbles;
// skip l in [P,P+512) (gemm writes those). LDS 48KB -> 3 blocks/CU.
__global__ __launch_bounds__(256, 3) void qkv_gemm_fused(
    const _Float16* __restrict__ X,
    const float* __restrict__ Wq,
    const float* __restrict__ Wk,
    const float* __restrict__ Wv,
    const float* __restrict__ cK,       // [32][4096][128] f32
    const float* __restrict__ cV,       // [32][4096][128] f32
    _Float16* __restrict__ Q16,
    _Float16* __restrict__ Kc,          // [32][4096][128] f16
    _Float16* __restrict__ Vt16,        // [32][128][4096] f16
    const int* __restrict__ Pp)
{
  __shared__ __align__(16) _Float16 smem[2 * (128 + 64) * 64];   // 48KB: dbuf As + Bs
  _Float16* As = smem;                    // 2 x 16KB, 128B rows, XOR-swizzled
  _Float16* Bs = smem + 2 * 128 * 64;     // 2 x 8KB,  128B rows, XOR-swizzled
  const int bid = blockIdx.x;
  const int tid = threadIdx.x;

  if (bid < 768) {
    // ================= GEMM path =================
    const int xcd = bid & 7, s = bid >> 3;
    const int nt = xcd * 24 + (s >> 2);
    const int mt = s & 3;
    const int m0 = mt * 128, n0 = nt * 64;
    const int wave = tid >> 6, lane = tid & 63;
    const int g = lane >> 4, c = lane & 15;
    const int wr = wave >> 1, wc = wave & 1;    // wave = 64m x 32n
    const float* Wp = (n0 < 4096) ? Wq : ((n0 < 8192) ? Wk : Wv);
    const int n0l = n0 & 4095;
    const int ar  = lane >> 3;
    const int acs = (lane & 7) * 16;
    const int brow = tid >> 2;
    const int bc32 = (tid & 3) * 16;
    const float* wsrc = Wp + (size_t)(n0l + brow) * 4096 + bc32;
    const int bsw = (brow & 7) << 4;

    float4 breg[4];
    auto loadB = [&](int k0) {
      const float* ns = wsrc + k0;
#pragma unroll
      for (int i = 0; i < 4; i++) breg[i] = *(const float4*)(ns + i * 4);
    };
    auto writeB = [&](int buf) {
      const float* bv = (const float*)breg;
      f16x8 h0, h1;
#pragma unroll
      for (int i = 0; i < 8; i++) { h0[i] = (_Float16)bv[i]; h1[i] = (_Float16)bv[8 + i]; }
      char* rb = (char*)Bs + buf * 8192 + brow * 128;
      *(f16x8*)(rb + (((tid & 3) * 32)      ^ bsw)) = h0;
      *(f16x8*)(rb + (((tid & 3) * 32 + 16) ^ bsw)) = h1;
    };
    auto stageA = [&](int k0, int buf) {
#pragma unroll
      for (int p = 0; p < 4; p++) {
        int chunk = wave * 4 + p;
        int row = chunk * 8 + ar;
        gload_lds16((const char*)(X + (size_t)(m0 + row) * 4096 + k0) + (acs ^ ((row & 7) << 4)),
                    (char*)As + buf * 16384 + chunk * 1024);
      }
    };

    f32x4 acc[4][2] = {};
    loadB(0);
    writeB(0);
    stageA(0, 0);
    loadB(64);
    __syncthreads();

    for (int t = 0; t < 64; ++t) {
      const int cur = t & 1, nxt = cur ^ 1;
      writeB(nxt);                         // B(t+1): regs loaded one iter ago
      loadB(((t + 2) & 63) << 6);          // B(t+2) regs in flight
      stageA(((t + 1) & 63) << 6, nxt);    // A(t+1) async -> lands during compute
      const char* Ab = (const char*)As + cur * 16384;
      const char* Bb = (const char*)Bs + cur * 8192;
      f16x8 af[2][4], bf[2][2];
#pragma unroll
      for (int mi = 0; mi < 4; mi++) {
        int row = wr * 64 + mi * 16 + c;
        int sw = (row & 7) << 4;
#pragma unroll
        for (int kc = 0; kc < 2; kc++)
          af[kc][mi] = *(const f16x8*)(Ab + row * 128 + ((kc * 64 + g * 16) ^ sw));
      }
#pragma unroll
      for (int ni = 0; ni < 2; ni++) {
        int row = wc * 32 + ni * 16 + c;
        int sw = (row & 7) << 4;
#pragma unroll
        for (int kc = 0; kc < 2; kc++)
          bf[kc][ni] = *(const f16x8*)(Bb + row * 128 + ((kc * 64 + g * 16) ^ sw));
      }
#pragma unroll
      for (int kc = 0; kc < 2; kc++)
#pragma unroll
        for (int mi = 0; mi < 4; mi++)
#pragma unroll
          for (int ni = 0; ni < 2; ni++)
            acc[mi][ni] = MFMA16(af[kc][mi], bf[kc][ni], acc[mi][ni]);
      __syncthreads();                     // ONE barrier/iter
    }

    const int p = Pp[0];
    const int wsel = n0 >> 12;
    const int h = (n0 & 4095) >> 7;
    const int dbase = n0 & 127;
#pragma unroll
    for (int mi = 0; mi < 4; mi++) {
#pragma unroll
      for (int ni = 0; ni < 2; ni++) {
#pragma unroll
        for (int j = 0; j < 4; j++) {
          int m = m0 + wr * 64 + mi * 16 + 4 * g + j;
          int d = dbase + wc * 32 + ni * 16 + c;
          _Float16 hv = (_Float16)acc[mi][ni][j];
          if (wsel == 0)      Q16[(size_t)(h * 512 + m) * 128 + d] = hv;
          else if (wsel == 1) Kc[(size_t)(h * 4096 + p + m) * 128 + d] = hv;
          else                Vt16[((size_t)h * 128 + d) * 4096 + p + m] = hv;
        }
      }
    }
    return;
  }

  // ================= cvt paths =================
  const int p = Pp[0];
  const int cb = bid - 768;
  if (cb < 512) {
    // ---- cache_K f32 -> K16 f16 (same layout), skip rows [P,P+512) ----
    const int total = 32 * 4096 * 16;          // f16x8 chunks
    const int stride = 512 * 256;
    for (int i = cb * 256 + tid; i < total; i += stride) {
      int l = (i >> 4) & 4095;
      if ((unsigned)(l - p) < 512u) continue;
      const float4* s = (const float4*)cK + 2 * (size_t)i;
      float4 a = s[0], b = s[1];
      f16x8 o;
      o[0]=(_Float16)a.x; o[1]=(_Float16)a.y; o[2]=(_Float16)a.z; o[3]=(_Float16)a.w;
      o[4]=(_Float16)b.x; o[5]=(_Float16)b.y; o[6]=(_Float16)b.z; o[7]=(_Float16)b.w;
      ((f16x8*)Kc)[i] = o;
    }
  } else {
    // ---- cache_V f32 -> V^T f16, skip cols [P,P+512); pad 74 (2-way banks, free) ----
    _Float16 (*t)[74] = (_Float16 (*)[74])smem;   // 64x74 f16 = 9.3KB
    const int r = tid >> 4, c4 = (tid & 15) * 4;
    const int d = tid >> 2, lc = (tid & 3) * 16;
#pragma unroll
    for (int rep = 0; rep < 2; rep++) {
      int b = (cb - 512) * 2 + rep;            // 0..4095: 32 h x 64 l x 2 d tiles
      int h = b >> 7, rest = b & 127;
      int lt = rest >> 1, dt = rest & 1;
      int l0 = lt * 64, d0 = dt * 64;
      __syncthreads();
#pragma unroll
      for (int i = 0; i < 4; i++) {
        int l = r + i * 16;
        float4 v = *(const float4*)&cV[((size_t)h * 4096 + l0 + l) * 128 + d0 + c4];
        t[c4 + 0][l] = (_Float16)v.x;
        t[c4 + 1][l] = (_Float16)v.y;
        t[c4 + 2][l] = (_Float16)v.z;
        t[c4 + 3][l] = (_Float16)v.w;
      }
      __syncthreads();
#pragma unroll
      for (int i = 0; i < 2; i++) {
        int l = l0 + lc + i * 8;               // 8-l chunk; P is 8-aligned
        if ((unsigned)(l - p) < 512u) continue;
        f16x8 o = *(const f16x8*)&t[d][lc + i * 8];
        *(f16x8*)&Vt16[((size_t)h * 128 + d0 + d) * 4096 + l] = o;
      }
    }
  }
}

// ---------------- flash attention: split-L=4, 128 q-rows/block, 2 blocks/CU ----------------
__global__ __launch_bounds__(512, 2) void attn_part(
    const _Float16* __restrict__ Q16,
    const _Float16* __restrict__ Kc,     // [32][4096][128]
    const _Float16* __restrict__ Vt,     // [32][128][4096]
    _Float16* __restrict__ Opart,        // [4][32][512][128] f16
    float* __restrict__ Mpart,           // [4][32][512]
    float* __restrict__ Lpart)           // [4][32][512]
{
  __shared__ __align__(16) _Float16 Ks[64 * 128];     // 16KB
  __shared__ __align__(16) _Float16 Vs[128 * 64];     // 16KB
  __shared__ __align__(16) _Float16 Pl[8][16][68];    // 17KB
  const int bid = blockIdx.x;
  const int xcd = bid & 7, s = bid >> 3;
  const int group = xcd * 16 + (s >> 2);              // ls*32+h
  const int mt = s & 3;
  const int ls = group >> 5, h = group & 31;
  const int m0 = mt * 128;
  const int tid = threadIdx.x, wave = tid >> 6, lane = tid & 63;
  const int g = lane >> 4, c = lane & 15;
  const int mw = m0 + wave * 16;
  const _Float16* Kh  = Kc + (size_t)h * 4096 * 128;
  const _Float16* Vth = Vt + (size_t)h * 128 * 4096;
  f16x8 qf[4];
#pragma unroll
  for (int kc = 0; kc < 4; kc++)
    qf[kc] = *(const f16x8*)&Q16[(size_t)(h * 512 + mw + c) * 128 + kc * 32 + g * 8];
  f32x4 o[8] = {};
  float mrow[4] = {-3e38f, -3e38f, -3e38f, -3e38f};
  float lrow[4] = {0.f, 0.f, 0.f, 0.f};
  const int klr = lane >> 4, klb = (lane & 15) * 16;
  const int vlr = lane >> 3, vlb = (lane & 7) * 16;

  const int l_begin = ls * 1024;
  for (int l0 = l_begin; l0 < l_begin + 1024; l0 += 64) {
    __syncthreads();
#pragma unroll
    for (int p = 0; p < 2; p++) {
      int chunk = p * 8 + wave;
      int kr = chunk * 4 + klr;
      gload_lds16((const char*)Kh + (size_t)(l0 + kr) * 256 + (klb ^ ((kr & 7) << 4)),
                  (char*)Ks + chunk * 1024);
      int vd = chunk * 8 + vlr;
      gload_lds16((const char*)Vth + (size_t)vd * 8192 + (size_t)l0 * 2 + (vlb ^ ((vd & 7) << 4)),
                  (char*)Vs + chunk * 1024);
    }
    __syncthreads();
    f32x4 sc[4] = {};
#pragma unroll
    for (int ni = 0; ni < 4; ni++) {
      int kr = ni * 16 + c;
      f16x8 kf[4];
#pragma unroll
      for (int kc = 0; kc < 4; kc++)
        kf[kc] = *(const f16x8*)((const char*)Ks + kr * 256 + ((kc * 64 + g * 16) ^ ((kr & 7) << 4)));
#pragma unroll
      for (int kc = 0; kc < 4; kc++)
        sc[ni] = MFMA16(qf[kc], kf[kc], sc[ni]);
    }
    float scale[4];
#pragma unroll
    for (int j = 0; j < 4; j++) {
      float tm = sc[0][j];
#pragma unroll
      for (int ni = 1; ni < 4; ni++) tm = fmaxf(tm, sc[ni][j]);
      tm = fmaxf(tm, __shfl_xor(tm, 1, 64));
      tm = fmaxf(tm, __shfl_xor(tm, 2, 64));
      tm = fmaxf(tm, __shfl_xor(tm, 4, 64));
      tm = fmaxf(tm, __shfl_xor(tm, 8, 64));
      float mn = fmaxf(mrow[j], tm);
      scale[j] = __expf(mrow[j] - mn);
      mrow[j] = mn;
    }
    float rs[4] = {0.f, 0.f, 0.f, 0.f};
#pragma unroll
    for (int ni = 0; ni < 4; ni++) {
#pragma unroll
      for (int j = 0; j < 4; j++) {
        float pv = __expf(sc[ni][j] - mrow[j]);
        sc[ni][j] = pv;
        rs[j] += pv;
      }
    }
#pragma unroll
    for (int j = 0; j < 4; j++) {
      rs[j] += __shfl_xor(rs[j], 1, 64);
      rs[j] += __shfl_xor(rs[j], 2, 64);
      rs[j] += __shfl_xor(rs[j], 4, 64);
      rs[j] += __shfl_xor(rs[j], 8, 64);
      lrow[j] = lrow[j] * scale[j] + rs[j];
    }
#pragma unroll
    for (int dn = 0; dn < 8; dn++)
#pragma unroll
      for (int j = 0; j < 4; j++) o[dn][j] *= scale[j];
#pragma unroll
    for (int ni = 0; ni < 4; ni++)
#pragma unroll
      for (int j = 0; j < 4; j++)
        Pl[wave][4 * g + j][ni * 16 + c] = (_Float16)sc[ni][j];
    f16x8 pa[2];
#pragma unroll
    for (int kc = 0; kc < 2; kc++)
      pa[kc] = *(const f16x8*)&Pl[wave][c][kc * 32 + g * 8];
#pragma unroll
    for (int dn = 0; dn < 8; dn++) {
      int vr = dn * 16 + c;
#pragma unroll
      for (int kc = 0; kc < 2; kc++) {
        f16x8 vb = *(const f16x8*)((const char*)Vs + vr * 128 + ((kc * 64 + g * 16) ^ ((vr & 7) << 4)));
        o[dn] = MFMA16(pa[kc], vb, o[dn]);
      }
    }
  }
  const size_t pbase = ((size_t)(ls * 32 + h) * 512);
#pragma unroll
  for (int dn = 0; dn < 8; dn++) {
#pragma unroll
    for (int j = 0; j < 4; j++) {
      int m = mw + 4 * g + j;
      Opart[(pbase + m) * 128 + dn * 16 + c] = (_Float16)o[dn][j];
    }
  }
  if (c == 0) {
#pragma unroll
    for (int j = 0; j < 4; j++) {
      int m = mw + 4 * g + j;
      Mpart[pbase + m] = mrow[j];
      Lpart[pbase + m] = lrow[j];
    }
  }
}

// ---------------- combine 4 split-L partials (f16 Opart) ----------------
__global__ __launch_bounds__(256) void attn_combine(
    const _Float16* __restrict__ Opart,
    const float* __restrict__ Mpart,
    const float* __restrict__ Lpart,
    float* __restrict__ out)
{
  int idx = blockIdx.x * 256 + threadIdx.x;
  int row = idx >> 5;
  int d4  = idx & 31;
  int h = row >> 9, m = row & 511;
  float Ms[4];
  float mx = -3e38f;
#pragma unroll
  for (int s = 0; s < 4; s++) {
    Ms[s] = Mpart[(size_t)(s * 32 + h) * 512 + m];
    mx = fmaxf(mx, Ms[s]);
  }
  float lsum = 0.f;
  float4 acc = make_float4(0.f, 0.f, 0.f, 0.f);
#pragma unroll
  for (int s = 0; s < 4; s++) {
    float w = __expf(Ms[s] - mx);
    lsum += w * Lpart[(size_t)(s * 32 + h) * 512 + m];
    f16x4 ov = *(const f16x4*)(Opart + ((size_t)(s * 32 + h) * 512 + m) * 128 + d4 * 4);
    acc.x += w * (float)ov[0]; acc.y += w * (float)ov[1];
    acc.z += w * (float)ov[2]; acc.w += w * (float)ov[3];
  }
  float inv = 1.f / lsum;
  float4 r = make_float4(acc.x * inv, acc.y * inv, acc.z * inv, acc.w * inv);
  *(float4*)&out[(size_t)m * 4096 + h * 128 + d4 * 4] = r;
}

extern "C" void kernel_launch(void* const* d_in, const int* in_sizes, int n_in,
                              void* d_out, int out_size, void* d_ws, size_t ws_size,
                              hipStream_t stream) {
  const float* X  = (const float*)d_in[0];
  const float* Wq = (const float*)d_in[1];
  const float* Wk = (const float*)d_in[2];
  const float* Wv = (const float*)d_in[3];
  const float* cK = (const float*)d_in[4];
  const float* cV = (const float*)d_in[5];
  const int*   Pp = (const int*)d_in[6];
  float* out = (float*)d_out;

  char* ws = (char*)d_ws;
  _Float16* X16  = (_Float16*)(ws);                           // 0..4 MB
  _Float16* Opart = (_Float16*)(ws + ((size_t)4  << 20));     // 4..20 MB [4][32][512][128] f16
  float* Mpart = (float*)(ws + ((size_t)36 << 20));
  float* Lpart = (float*)(ws + ((size_t)37 << 20));
  _Float16* Q16  = (_Float16*)(ws + ((size_t)100 << 20));     // 100..104
  _Float16* K16  = (_Float16*)(ws + ((size_t)104 << 20));     // 104..136 [32][4096][128]
  _Float16* V16t = (_Float16*)(ws + ((size_t)136 << 20));     // 136..168 [32][128][4096]

  cvt_f32_f16<<<dim3(1024), dim3(256), 0, stream>>>(X, X16, 512 * 4096 / 8);
  qkv_gemm_fused<<<dim3(768 + 512 + 2048), dim3(256), 0, stream>>>(
      X16, Wq, Wk, Wv, cK, cV, Q16, K16, V16t, Pp);
  attn_part<<<dim3(512), dim3(512), 0, stream>>>(Q16, K16, V16t, Opart, Mpart, Lpart);
  attn_combine<<<dim3(2048), dim3(256), 0, stream>>>(Opart, Mpart, Lpart, out);
}